// Round 8
// baseline (1697.545 us; speedup 1.0000x reference)
//
#include <hip/hip_runtime.h>
#include <cstddef>
#include <cstdint>

constexpr int NB = 256;
constexpr int NT = 512;
constexpr int NV = 32;

typedef _Float16 h2_t __attribute__((ext_vector_type(2)));

__device__ __forceinline__ float sigmoidf_(float x){ return 1.0f/(1.0f+__expf(-x)); }
__device__ __forceinline__ float tanhf_(float x){ return 1.0f - 2.0f/(__expf(2.0f*x)+1.0f); }

__device__ __forceinline__ uint32_t pack2u_(float a, float b){
  h2_t r; r.x=(_Float16)a; r.y=(_Float16)b; return __builtin_bit_cast(uint32_t, r);
}
__device__ __forceinline__ float dot2u_(uint32_t u, uint32_t w, float c){
#if __has_builtin(__builtin_amdgcn_fdot2)
  return __builtin_amdgcn_fdot2(__builtin_bit_cast(h2_t,u), __builtin_bit_cast(h2_t,w), c, false);
#else
  h2_t a=__builtin_bit_cast(h2_t,u), b=__builtin_bit_cast(h2_t,w);
  return c + (float)a.x*(float)b.x + (float)a.y*(float)b.y;
#endif
}

// ---------------- stats + x_comp ----------------
__global__ __launch_bounds__(256) void k_stats(
    const float* __restrict__ values, const float* __restrict__ masks,
    const int* __restrict__ lengths,
    float* __restrict__ x_comp, float* __restrict__ stats)
{
  const int b = blockIdx.x;
  const int v = threadIdx.x & 31;
  const int g = threadIdx.x >> 5;
  const int len = lengths[b];
  const float* vb = values + (size_t)b*NT*NV;
  const float* mb = masks  + (size_t)b*NT*NV;
  float* xb = x_comp + (size_t)b*NT*NV;
  float s_m=0.f, s_mv=0.f, s_v=0.f, s_v2=0.f;
  for (int t=g; t<NT; t+=8){
    float val = vb[t*NV+v];
    float m   = mb[t*NV+v];
    float xp  = (t==0) ? vb[v] : vb[(t-1)*NV+v];
    float pm  = (t<len) ? 1.0f : 0.0f;
    xb[t*NV+v] = (m*val + (1.0f-m)*xp)*pm;
    s_m += m; s_mv += m*val; s_v += val; s_v2 += val*val;
  }
  __shared__ float red[4][8][32];
  red[0][g][v]=s_m; red[1][g][v]=s_mv; red[2][g][v]=s_v; red[3][g][v]=s_v2;
  __syncthreads();
  if (g==0){
    float a0=0,a1=0,a2=0,a3=0;
    #pragma unroll
    for(int i=0;i<8;i++){ a0+=red[0][i][v]; a1+=red[1][i][v]; a2+=red[2][i][v]; a3+=red[3][i][v]; }
    float msum = fmaxf(a0, 1.0f);
    float mean = a1/msum;
    float dss  = a3 - 2.0f*mean*a2 + (float)NT*mean*mean;
    float var  = (msum > 1.0f) ? dss/(msum-1.0f) : 0.0f;
    float sd   = sqrtf(fmaxf(var, 0.0f));
    float miss = 1.0f - a0 / fmaxf((float)len, 1.0f);
    float* st = stats + b*97;
    if (v==0) st[0] = (float)len;
    st[1+v]=mean; st[33+v]=sd; st[65+v]=miss;
  }
}

// ---------------- context MLP ----------------
__global__ __launch_bounds__(64) void k_cmlp(
    const float* __restrict__ stats,
    const float* __restrict__ W1, const float* __restrict__ b1,
    const float* __restrict__ W2, const float* __restrict__ b2,
    float* __restrict__ ctx)
{
  const int b = blockIdx.x;
  const int j = threadIdx.x;
  __shared__ float st[97];
  __shared__ float hm[64];
  for (int k=j; k<97; k+=64) st[k] = stats[b*97+k];
  __syncthreads();
  float a0=b1[j], a1=0.f, a2=0.f, a3=0.f;
  #pragma unroll
  for (int k=0; k<96; k+=4){
    a0 += st[k]*W1[j*97+k];     a1 += st[k+1]*W1[j*97+k+1];
    a2 += st[k+2]*W1[j*97+k+2]; a3 += st[k+3]*W1[j*97+k+3];
  }
  a0 += st[96]*W1[j*97+96];
  hm[j] = fmaxf((a0+a1)+(a2+a3), 0.0f);
  __syncthreads();
  if (j < 32){
    float c0_=b2[j], c1=0.f, c2=0.f, c3=0.f;
    #pragma unroll
    for (int k=0;k<64;k+=4){
      c0_ += hm[k]*W2[j*64+k];    c1 += hm[k+1]*W2[j*64+k+1];
      c2 += hm[k+2]*W2[j*64+k+2]; c3 += hm[k+3]*W2[j*64+k+3];
    }
    ctx[b*64+j] = (c0_+c1)+(c2+c3);
  }
}

// ---------------- GRU scan: LDS f16 weights, quarter-split, 1 batch/block ----------------
__global__ __launch_bounds__(512) void k_gru(
    const float* __restrict__ x_comp, const float* __restrict__ rain_f,
    const float* __restrict__ rain_bw, const int* __restrict__ lengths,
    const float* __restrict__ Wih, const float* __restrict__ Whh,
    const float* __restrict__ bih, const float* __restrict__ bhh,
    float* __restrict__ ctx)
{
  const int b = blockIdx.x;
  const int tid = threadIdx.x;
  const int j = tid & 127;
  const int q = tid >> 7;
  const bool act = (j < 96);
  int len = lengths[b]; if (len > NT) len = NT;
  __shared__ uint32_t WT[4][16][96];    // [part][k][gate] packed f16 pairs (24 KB)
  __shared__ __align__(16) uint32_t u2[2][48]; // packed x|rf|rb
  __shared__ __align__(16) uint32_t hp[16];    // packed h
  __shared__ float gpart[4][96];
  for (int idx = tid; idx < 4*16*96; idx += 512){
    const int qq = idx / (16*96);
    const int r1 = idx - qq*16*96;
    const int kk = r1 / 96;
    const int jj = r1 - kk*96;
    float a, c2;
    if (qq < 3){ a = Wih[jj*96 + qq*32 + 2*kk]; c2 = Wih[jj*96 + qq*32 + 2*kk + 1]; }
    else       { a = Whh[jj*32 + 2*kk];          c2 = Whh[jj*32 + 2*kk + 1]; }
    WT[qq][kk][jj] = pack2u_(a, c2);
  }
  float b0 = 0.f;
  if (act){ if (q == 0) b0 = bih[j]; else if (q == 3) b0 = bhh[j]; }
  const float* xc = x_comp + (size_t)b*NT*NV;
  const float* rf = rain_f + (size_t)b*NT*NV;
  const float* rb = rain_bw + (size_t)b*NT*NV;
  if (tid < 16) hp[tid] = 0u;
  float h_reg = 0.0f;
  if (tid >= 128 && tid < 224){
    const int idx = tid - 128;
    const float v = (idx<32) ? xc[idx] : (idx<64 ? rf[idx-32] : rb[idx-64]);
    const float pr = __shfl_xor(v, 1);
    if (!(idx & 1)) u2[0][idx>>1] = pack2u_(v, pr);
  }
  __syncthreads();
  for (int t=0; t<len; ++t){
    const int cur = t & 1;
    float pf = 0.f;
    const bool dopf = (tid >= 128) && (tid < 224) && (t+1 < len);
    if (dopf){
      const int idx = tid - 128, tn = t+1;
      pf = (idx<32) ? xc[tn*NV+idx] : (idx<64 ? rf[tn*NV+idx-32] : rb[tn*NV+idx-64]);
    }
    if (act){
      const uint4* uu = (const uint4*)((q < 3) ? &u2[cur][q*16] : &hp[0]);
      const uint4 U0 = uu[0], U1 = uu[1], U2 = uu[2], U3 = uu[3];
      float acc = b0;
      acc = dot2u_(U0.x, WT[q][0][j],  acc); acc = dot2u_(U0.y, WT[q][1][j],  acc);
      acc = dot2u_(U0.z, WT[q][2][j],  acc); acc = dot2u_(U0.w, WT[q][3][j],  acc);
      acc = dot2u_(U1.x, WT[q][4][j],  acc); acc = dot2u_(U1.y, WT[q][5][j],  acc);
      acc = dot2u_(U1.z, WT[q][6][j],  acc); acc = dot2u_(U1.w, WT[q][7][j],  acc);
      acc = dot2u_(U2.x, WT[q][8][j],  acc); acc = dot2u_(U2.y, WT[q][9][j],  acc);
      acc = dot2u_(U2.z, WT[q][10][j], acc); acc = dot2u_(U2.w, WT[q][11][j], acc);
      acc = dot2u_(U3.x, WT[q][12][j], acc); acc = dot2u_(U3.y, WT[q][13][j], acc);
      acc = dot2u_(U3.z, WT[q][14][j], acc); acc = dot2u_(U3.w, WT[q][15][j], acc);
      gpart[q][j] = acc;
    }
    if (dopf){
      const int idx = tid - 128;
      const float pr = __shfl_xor(pf, 1);
      if (!(idx & 1)) u2[cur^1][idx>>1] = pack2u_(pf, pr);
    }
    __syncthreads();
    if (tid < 32){
      const float gr  = gpart[0][tid] + gpart[1][tid] + gpart[2][tid] + gpart[3][tid];
      const float gz  = gpart[0][32+tid] + gpart[1][32+tid] + gpart[2][32+tid] + gpart[3][32+tid];
      const float gni = gpart[0][64+tid] + gpart[1][64+tid] + gpart[2][64+tid];
      const float gnh = gpart[3][64+tid];
      const float r = sigmoidf_(gr);
      const float z = sigmoidf_(gz);
      const float n = tanhf_(gni + r*gnh);
      h_reg = (1.0f - z)*n + z*h_reg;
      const float pr = __shfl_xor(h_reg, 1);
      if (!(tid & 1)) hp[tid>>1] = pack2u_(h_reg, pr);
    }
    __syncthreads();
  }
  if (tid < 32) ctx[b*64 + 32 + tid] = h_reg;
}

// ---------------- init: h0/c0, ctx-part of LSTM gates, hidden seeds ----------------
__global__ __launch_bounds__(256) void k_init(
    const float* __restrict__ ctx,
    const float* __restrict__ initW, const float* __restrict__ initb,
    const float* __restrict__ WihF, const float* __restrict__ bihF, const float* __restrict__ bhhF,
    const float* __restrict__ WihB, const float* __restrict__ bihB, const float* __restrict__ bhhB,
    float* __restrict__ h0, float* __restrict__ c0,
    float* __restrict__ cgF, float* __restrict__ cgB,
    float* __restrict__ hidden)
{
  const int b = blockIdx.x;
  const int j = threadIdx.x;
  __shared__ __align__(16) float cv[64];
  if (j < 64) cv[j] = ctx[b*64+j];
  __syncthreads();
  {
    float4 f = {bihF[j]+bhhF[j], 0.f, 0.f, 0.f};
    float4 g = {bihB[j]+bhhB[j], 0.f, 0.f, 0.f};
    #pragma unroll
    for (int q=0;q<16;q++){
      const float4 cvv = *(const float4*)&cv[4*q];
      const float4 wf = *(const float4*)(WihF + (size_t)j*128 + 64 + 4*q);
      const float4 wb = *(const float4*)(WihB + (size_t)j*128 + 64 + 4*q);
      f.x += cvv.x*wf.x; f.y += cvv.y*wf.y; f.z += cvv.z*wf.z; f.w += cvv.w*wf.w;
      g.x += cvv.x*wb.x; g.y += cvv.y*wb.y; g.z += cvv.z*wb.z; g.w += cvv.w*wb.w;
    }
    cgF[b*256+j] = (f.x+f.y)+(f.z+f.w);
    cgB[b*256+j] = (g.x+g.y)+(g.z+g.w);
  }
  if (j < 128){
    float4 a = {initb[j], 0.f, 0.f, 0.f};
    #pragma unroll
    for (int q=0;q<16;q++){
      const float4 cvv = *(const float4*)&cv[4*q];
      const float4 w  = *(const float4*)(initW + (size_t)j*64 + 4*q);
      a.x += cvv.x*w.x; a.y += cvv.y*w.y; a.z += cvv.z*w.z; a.w += cvv.w*w.w;
    }
    float hv = (a.x+a.y)+(a.z+a.w);
    h0[b*128+j] = hv;
    c0[b*128+j] = tanhf_(hv);
    if (j < 64) hidden[(size_t)b*NT*128 + j] = hv;                                // fwd seed t=0
    else        hidden[(size_t)b*NT*128 + (size_t)(NT-1)*128 + 64 + (j-64)] = hv; // bwd seed t=T-1
  }
}

// ---------------- LSTM scans: LDS f16 weights, 4 batch cols/block, half-split ----------------
// dynamic LDS layout (75264 B):
//   WxT[32][256] @0        (32 KB)  word k of Wih[j][0:64] pairs, [k][gate]
//   WhT[32][256] @32768    (32 KB)
//   u2[2][4][32] @65536    (1 KB)   packed x|mask per col, dbuf
//   hw[4][32]    @66560    (512 B)  packed h per col
//   gpart[2][4][256] @67072 (8 KB)
__global__ __launch_bounds__(512) void k_lstm(
    const float* __restrict__ x_comp, const float* __restrict__ masks,
    const float* __restrict__ WihF, const float* __restrict__ WhhF,
    const float* __restrict__ WihB, const float* __restrict__ WhhB,
    const float* __restrict__ cgF, const float* __restrict__ cgB,
    const float* __restrict__ h0, const float* __restrict__ c0,
    const int* __restrict__ lengths,
    float* __restrict__ hidden)
{
  extern __shared__ char smem_[];
  uint32_t (*WxT)[256]    = (uint32_t(*)[256])(smem_);
  uint32_t (*WhT)[256]    = (uint32_t(*)[256])(smem_ + 32768);
  uint32_t (*u2)[4][32]   = (uint32_t(*)[4][32])(smem_ + 65536);
  uint32_t (*hw)[32]      = (uint32_t(*)[32])(smem_ + 66560);
  float    (*gpart)[4][256] = (float(*)[4][256])(smem_ + 67072);
  const int quad = blockIdx.x;
  const int dir  = blockIdx.y;
  const int tid = threadIdx.x;
  const int j = tid & 255;
  const int half = tid >> 8;
  const int b0 = quad*4;
  const float* Wih = dir ? WihB : WihF;
  const float* Whh = dir ? WhhB : WhhF;
  const float* cgp = dir ? cgB : cgF;
  for (int idx = tid; idx < 32*256; idx += 512){
    const int k = idx >> 8, r = idx & 255;
    WxT[k][r] = pack2u_(Wih[(size_t)r*128 + 2*k], Wih[(size_t)r*128 + 2*k + 1]);
    WhT[k][r] = pack2u_(Whh[(size_t)r*64  + 2*k], Whh[(size_t)r*64  + 2*k + 1]);
  }
  int nsteps = NT-1;
  if (dir == 0){
    int ml = 0;
    #pragma unroll
    for (int c=0;c<4;c++){ const int l = lengths[b0+c]; if (l>ml) ml=l; }
    int e = ml-1; if (e<0) e=0; if (e<nsteps) nsteps = e;
  }
  float cg0=0.f, cg1=0.f, cg2=0.f, cg3=0.f;
  if (!half){
    cg0 = cgp[(b0+0)*256 + j]; cg1 = cgp[(b0+1)*256 + j];
    cg2 = cgp[(b0+2)*256 + j]; cg3 = cgp[(b0+3)*256 + j];
  }
  float cst = 0.f;
  if (tid < 256){
    const int col = tid >> 6, hi = tid & 63;
    const float hv = h0[(b0+col)*128 + dir*64 + hi];
    cst            = c0[(b0+col)*128 + dir*64 + hi];
    const float pr = __shfl_xor(hv, 1);
    if (!(hi & 1)) hw[col][hi>>1] = pack2u_(hv, pr);
  } else if (nsteps > 0){
    const int pid = tid - 256;
    const int col = pid >> 6, idx = pid & 63;
    const int t0 = dir ? NT-1 : 0;
    const float* xc = x_comp + (size_t)(b0+col)*NT*NV;
    const float* mk = masks  + (size_t)(b0+col)*NT*NV;
    const float v = (idx<32) ? xc[t0*NV+idx] : mk[t0*NV+idx-32];
    const float pr = __shfl_xor(v, 1);
    if (!(idx & 1)) u2[0][col][idx>>1] = pack2u_(v, pr);
  }
  const uint32_t (*WTsel)[256] = half ? WhT : WxT;
  __syncthreads();
  for (int s=0; s<nsteps; ++s){
    const int cur = s & 1;
    float pf = 0.f;
    int pcol = 0, pidx = 0;
    const bool dopf = (tid >= 256) && (s+1 < nsteps);
    if (dopf){
      const int pid = tid - 256;
      pcol = pid >> 6; pidx = pid & 63;
      const int tn = dir ? (NT-2-s) : (s+1);
      const float* xc = x_comp + (size_t)(b0+pcol)*NT*NV;
      const float* mk = masks  + (size_t)(b0+pcol)*NT*NV;
      pf = (pidx<32) ? xc[tn*NV+pidx] : mk[tn*NV+pidx-32];
    }
    uint32_t wv[32];
    #pragma unroll
    for (int k=0;k<32;k++) wv[k] = WTsel[k][j];
    float a0=cg0, a1=cg1, a2=cg2, a3=cg3;
    #define COLDOT(accv, cidx) { \
      const uint4* uu = (const uint4*)(half ? hw[cidx] : u2[cur][cidx]); \
      const uint4 U0=uu[0], U1=uu[1], U2=uu[2], U3=uu[3]; \
      const uint4 U4=uu[4], U5=uu[5], U6=uu[6], U7=uu[7]; \
      accv = dot2u_(U0.x, wv[0],  accv); accv = dot2u_(U0.y, wv[1],  accv); \
      accv = dot2u_(U0.z, wv[2],  accv); accv = dot2u_(U0.w, wv[3],  accv); \
      accv = dot2u_(U1.x, wv[4],  accv); accv = dot2u_(U1.y, wv[5],  accv); \
      accv = dot2u_(U1.z, wv[6],  accv); accv = dot2u_(U1.w, wv[7],  accv); \
      accv = dot2u_(U2.x, wv[8],  accv); accv = dot2u_(U2.y, wv[9],  accv); \
      accv = dot2u_(U2.z, wv[10], accv); accv = dot2u_(U2.w, wv[11], accv); \
      accv = dot2u_(U3.x, wv[12], accv); accv = dot2u_(U3.y, wv[13], accv); \
      accv = dot2u_(U3.z, wv[14], accv); accv = dot2u_(U3.w, wv[15], accv); \
      accv = dot2u_(U4.x, wv[16], accv); accv = dot2u_(U4.y, wv[17], accv); \
      accv = dot2u_(U4.z, wv[18], accv); accv = dot2u_(U4.w, wv[19], accv); \
      accv = dot2u_(U5.x, wv[20], accv); accv = dot2u_(U5.y, wv[21], accv); \
      accv = dot2u_(U5.z, wv[22], accv); accv = dot2u_(U5.w, wv[23], accv); \
      accv = dot2u_(U6.x, wv[24], accv); accv = dot2u_(U6.y, wv[25], accv); \
      accv = dot2u_(U6.z, wv[26], accv); accv = dot2u_(U6.w, wv[27], accv); \
      accv = dot2u_(U7.x, wv[28], accv); accv = dot2u_(U7.y, wv[29], accv); \
      accv = dot2u_(U7.z, wv[30], accv); accv = dot2u_(U7.w, wv[31], accv); }
    COLDOT(a0, 0) COLDOT(a1, 1) COLDOT(a2, 2) COLDOT(a3, 3)
    #undef COLDOT
    gpart[half][0][j] = a0; gpart[half][1][j] = a1;
    gpart[half][2][j] = a2; gpart[half][3][j] = a3;
    if (dopf){
      const float pr = __shfl_xor(pf, 1);
      if (!(pidx & 1)) u2[cur^1][pcol][pidx>>1] = pack2u_(pf, pr);
    }
    __syncthreads();
    if (tid < 256){
      const int col = tid >> 6, hi = tid & 63;
      const float gi = gpart[0][col][hi]     + gpart[1][col][hi];
      const float gf = gpart[0][col][64+hi]  + gpart[1][col][64+hi];
      const float gg = gpart[0][col][128+hi] + gpart[1][col][128+hi];
      const float go = gpart[0][col][192+hi] + gpart[1][col][192+hi];
      cst = sigmoidf_(gf)*cst + sigmoidf_(gi)*tanhf_(gg);
      const float hh = sigmoidf_(go)*tanhf_(cst);
      const int t    = dir ? (NT-1-s) : s;
      const int outt = dir ? (t-1)    : (s+1);
      hidden[(size_t)(b0+col)*NT*128 + (size_t)outt*128 + dir*64 + hi] = hh;
      const float pr = __shfl_xor(hh, 1);
      if (!(hi & 1)) hw[col][hi>>1] = pack2u_(hh, pr);
    }
    __syncthreads();
  }
}

// ---------------- feature-regression: LDS f16 weights, 4 rows/iter ----------------
// dynamic LDS (76032 B):
//   WfT[16][1024] @0      (64 KB)  masked packed, [k][row]
//   nl1T[16][32] @65536   (2 KB)
//   xp[4][16]    @67584   (256 B)
//   hidp[4][32][16] @67840 (8 KB)
__global__ __launch_bounds__(512) void k_feat(
    const float* __restrict__ x_comp,
    const float* __restrict__ feat_W, const float* __restrict__ feat_b,
    const float* __restrict__ nl1_W, const float* __restrict__ nl1_b,
    const float* __restrict__ nl2_W, const float* __restrict__ nl2_b,
    float* __restrict__ feat_imp)
{
  extern __shared__ char smem_[];
  uint32_t (*WfT)[1024]   = (uint32_t(*)[1024])(smem_);
  uint32_t (*nl1T)[32]    = (uint32_t(*)[32])(smem_ + 65536);
  uint32_t (*xp)[16]      = (uint32_t(*)[16])(smem_ + 67584);
  uint32_t (*hidp)[32][16]= (uint32_t(*)[32][16])(smem_ + 67840);
  const int tid = threadIdx.x;
  const int lane = tid & 31;
  const int ig = tid >> 5;        // 0..15
  const int i0 = ig, i1 = ig + 16;
  for (int idx = tid; idx < 16*1024; idx += 512){
    const int k = idx >> 10, rr = idx & 1023;
    const int i = rr >> 5;
    float a = feat_W[(size_t)rr*32 + 2*k];
    float c2 = feat_W[(size_t)rr*32 + 2*k + 1];
    if (2*k == i) a = 0.f;
    if (2*k+1 == i) c2 = 0.f;
    WfT[k][rr] = pack2u_(a, c2);
  }
  for (int idx = tid; idx < 16*32; idx += 512){
    const int k = idx >> 5, g = idx & 31;
    nl1T[k][g] = pack2u_(nl1_W[g*32 + 2*k], nl1_W[g*32 + 2*k + 1]);
  }
  const float fb0 = feat_b[i0*32 + lane];
  const float fb1 = feat_b[i1*32 + lane];
  const float n1b = nl1_b[lane];
  const float n2w = nl2_W[lane];
  const float n2b = nl2_b[0];
  __syncthreads();
  const int NQ = (NB*NT)/4;
  for (int rq = blockIdx.x; rq < NQ; rq += gridDim.x){
    const int r = rq*4;
    if (tid < 128){
      const int qq = tid >> 5, v = tid & 31;
      const float xv = x_comp[(size_t)(r+qq)*32 + v];
      const float pr = __shfl_xor(xv, 1);
      if (!(v & 1)) xp[qq][v>>1] = pack2u_(xv, pr);
    }
    __syncthreads();
    uint32_t wa[16], wb[16];
    #pragma unroll
    for (int k=0;k<16;k++){ wa[k] = WfT[k][i0*32+lane]; wb[k] = WfT[k][i1*32+lane]; }
    float za[4], zb[4];
    #pragma unroll
    for (int qq=0;qq<4;qq++){
      const uint4* xq = (const uint4*)xp[qq];
      const uint4 X0=xq[0], X1=xq[1], X2=xq[2], X3=xq[3];
      float s0 = fb0, s1 = fb1;
      s0=dot2u_(X0.x,wa[0],s0);  s1=dot2u_(X0.x,wb[0],s1);
      s0=dot2u_(X0.y,wa[1],s0);  s1=dot2u_(X0.y,wb[1],s1);
      s0=dot2u_(X0.z,wa[2],s0);  s1=dot2u_(X0.z,wb[2],s1);
      s0=dot2u_(X0.w,wa[3],s0);  s1=dot2u_(X0.w,wb[3],s1);
      s0=dot2u_(X1.x,wa[4],s0);  s1=dot2u_(X1.x,wb[4],s1);
      s0=dot2u_(X1.y,wa[5],s0);  s1=dot2u_(X1.y,wb[5],s1);
      s0=dot2u_(X1.z,wa[6],s0);  s1=dot2u_(X1.z,wb[6],s1);
      s0=dot2u_(X1.w,wa[7],s0);  s1=dot2u_(X1.w,wb[7],s1);
      s0=dot2u_(X2.x,wa[8],s0);  s1=dot2u_(X2.x,wb[8],s1);
      s0=dot2u_(X2.y,wa[9],s0);  s1=dot2u_(X2.y,wb[9],s1);
      s0=dot2u_(X2.z,wa[10],s0); s1=dot2u_(X2.z,wb[10],s1);
      s0=dot2u_(X2.w,wa[11],s0); s1=dot2u_(X2.w,wb[11],s1);
      s0=dot2u_(X3.x,wa[12],s0); s1=dot2u_(X3.x,wb[12],s1);
      s0=dot2u_(X3.y,wa[13],s0); s1=dot2u_(X3.y,wb[13],s1);
      s0=dot2u_(X3.z,wa[14],s0); s1=dot2u_(X3.z,wb[14],s1);
      s0=dot2u_(X3.w,wa[15],s0); s1=dot2u_(X3.w,wb[15],s1);
      za[qq] = fmaxf(s0, 0.f); zb[qq] = fmaxf(s1, 0.f);
    }
    #pragma unroll
    for (int qq=0;qq<4;qq++){
      const float pa = __shfl_xor(za[qq], 1);
      const float pb = __shfl_xor(zb[qq], 1);
      if (!(lane & 1)){
        hidp[qq][i0][lane>>1] = pack2u_(za[qq], pa);
        hidp[qq][i1][lane>>1] = pack2u_(zb[qq], pb);
      }
    }
    __syncthreads();
    uint32_t nw[16];
    #pragma unroll
    for (int k=0;k<16;k++) nw[k] = nl1T[k][lane];
    float o[8];
    #pragma unroll
    for (int qq=0;qq<4;qq++){
      const uint4* h0p = (const uint4*)hidp[qq][i0];
      const uint4* h1p = (const uint4*)hidp[qq][i1];
      float s0 = n1b, s1 = n1b;
      #pragma unroll
      for (int c4=0;c4<4;c4++){
        const uint4 H0 = h0p[c4];
        const uint4 H1 = h1p[c4];
        s0=dot2u_(H0.x,nw[4*c4],s0);   s1=dot2u_(H1.x,nw[4*c4],s1);
        s0=dot2u_(H0.y,nw[4*c4+1],s0); s1=dot2u_(H1.y,nw[4*c4+1],s1);
        s0=dot2u_(H0.z,nw[4*c4+2],s0); s1=dot2u_(H1.z,nw[4*c4+2],s1);
        s0=dot2u_(H0.w,nw[4*c4+3],s0); s1=dot2u_(H1.w,nw[4*c4+3],s1);
      }
      o[2*qq]   = fmaxf(s0,0.f)*n2w;
      o[2*qq+1] = fmaxf(s1,0.f)*n2w;
    }
    #pragma unroll
    for (int m=0;m<8;m++){
      #pragma unroll
      for (int off=16; off>0; off>>=1) o[m] += __shfl_xor(o[m], off, 32);
    }
    if (lane == 0){
      #pragma unroll
      for (int qq=0;qq<4;qq++){
        feat_imp[(size_t)(r+qq)*32 + i0] = o[2*qq]   + n2b;
        feat_imp[(size_t)(r+qq)*32 + i1] = o[2*qq+1] + n2b;
      }
    }
    __syncthreads();
  }
}

// ---------------- rnn_imp GEMM + fuse + final: LDS f16 rimp ----------------
__global__ __launch_bounds__(512) void k_final(
    const float* __restrict__ values, const float* __restrict__ masks,
    const float* __restrict__ feat_imp, const float* __restrict__ hidden,
    const float* __restrict__ rimp_W, const float* __restrict__ rimp_b,
    const float* __restrict__ fuse_W, const float* __restrict__ fuse_b,
    const int* __restrict__ lengths, float* __restrict__ out)
{
  const int tid = threadIdx.x;
  const int v = tid & 31;
  const int grp = (tid >> 5) & 7;
  const int half = tid >> 8;
  __shared__ uint32_t rpT[64][32];             // [k][v] packed rimp pairs (8 KB)
  __shared__ __align__(16) uint32_t hrowp[8][64];
  __shared__ float rpart[8][32];
  __shared__ float bpart[8][32];
  for (int idx = tid; idx < 64*32; idx += 512){
    const int k = idx >> 5, vv = idx & 31;
    rpT[k][vv] = pack2u_(rimp_W[(size_t)vv*128 + 2*k], rimp_W[(size_t)vv*128 + 2*k+1]);
  }
  const float4* F4 = (const float4*)(fuse_W + (size_t)v*64 + 32);
  float fconst = 0.f;
  if (!half){
    fconst = fuse_b[v];
    #pragma unroll
    for (int q=0;q<8;q++){
      const float4 fw = *(const float4*)(fuse_W + (size_t)v*64 + 4*q);
      fconst += (fw.x+fw.y)+(fw.z+fw.w);
    }
  }
  const float rbias = rimp_b[v];
  __syncthreads();
  const int NOCT = (NB*NT)/8;
  for (int oc = blockIdx.x; oc < NOCT; oc += gridDim.x){
    const size_t base = (size_t)oc*8;
    __syncthreads();
    if (tid < 256){
      const float4 hv = ((const float4*)(hidden + base*128))[tid];
      const int row = tid >> 5;
      const int w0 = (tid & 31) << 1;
      hrowp[row][w0]   = pack2u_(hv.x, hv.y);
      hrowp[row][w0+1] = pack2u_(hv.z, hv.w);
    }
    __syncthreads();
    const size_t r = base + grp;
    float a = half ? 0.f : rbias;
    {
      const uint4* hp4 = (const uint4*)&hrowp[grp][half*32];
      #pragma unroll
      for (int c4=0;c4<8;c4++){
        const uint4 H = hp4[c4];
        a = dot2u_(H.x, rpT[half*32 + 4*c4][v],     a);
        a = dot2u_(H.y, rpT[half*32 + 4*c4 + 1][v], a);
        a = dot2u_(H.z, rpT[half*32 + 4*c4 + 2][v], a);
        a = dot2u_(H.w, rpT[half*32 + 4*c4 + 3][v], a);
      }
    }
    if (half){
      rpart[grp][v] = a;
      const float* mrow = masks + r*32;
      float m0=0,m1=0,m2=0,m3=0;
      #pragma unroll
      for (int q=0;q<8;q++){
        const float4 mv = *(const float4*)(mrow + 4*q);
        const float4 fv = F4[q];
        m0 = fmaf(mv.x, fv.x, m0); m1 = fmaf(mv.y, fv.y, m1);
        m2 = fmaf(mv.z, fv.z, m2); m3 = fmaf(mv.w, fv.w, m3);
      }
      bpart[grp][v] = (m0+m1)+(m2+m3);
    }
    __syncthreads();
    if (!half){
      const int bb = (int)(r >> 9);
      const int t  = (int)(r & 511);
      const int len = lengths[bb];
      const float rimp = a + rpart[grp][v];
      const float beta = sigmoidf_(fconst + bpart[grp][v]);
      const float fi = feat_imp[r*32+v];
      const float m  = masks[r*32+v];
      const float val= values[r*32+v];
      const float fz = beta*fi + (1.0f-beta)*rimp;
      const float o = m*val + (1.0f-m)*fz;
      out[r*32+v] = (t < len) ? o : 0.0f;
    }
  }
}

extern "C" void kernel_launch(void* const* d_in, const int* in_sizes, int n_in,
                              void* d_out, int out_size, void* d_ws, size_t ws_size,
                              hipStream_t stream) {
  const float* values   = (const float*)d_in[0];
  const float* masks    = (const float*)d_in[1];
  const float* rain_f   = (const float*)d_in[2];
  const float* rain_b   = (const float*)d_in[3];
  const float* cmlp_W1  = (const float*)d_in[4];
  const float* cmlp_b1  = (const float*)d_in[5];
  const float* cmlp_W2  = (const float*)d_in[6];
  const float* cmlp_b2  = (const float*)d_in[7];
  const float* gru_Wih  = (const float*)d_in[8];
  const float* gru_Whh  = (const float*)d_in[9];
  const float* gru_bih  = (const float*)d_in[10];
  const float* gru_bhh  = (const float*)d_in[11];
  const float* init_W   = (const float*)d_in[12];
  const float* init_b   = (const float*)d_in[13];
  const float* lstmf_Wih= (const float*)d_in[14];
  const float* lstmf_Whh= (const float*)d_in[15];
  const float* lstmf_bih= (const float*)d_in[16];
  const float* lstmf_bhh= (const float*)d_in[17];
  const float* lstmb_Wih= (const float*)d_in[18];
  const float* lstmb_Whh= (const float*)d_in[19];
  const float* lstmb_bih= (const float*)d_in[20];
  const float* lstmb_bhh= (const float*)d_in[21];
  const float* rimp_W   = (const float*)d_in[22];
  const float* rimp_b   = (const float*)d_in[23];
  const float* feat_W   = (const float*)d_in[24];
  const float* feat_b   = (const float*)d_in[25];
  const float* nl1_W    = (const float*)d_in[26];
  const float* nl1_b    = (const float*)d_in[27];
  const float* nl2_W    = (const float*)d_in[28];
  const float* nl2_b    = (const float*)d_in[29];
  const float* fuse_W   = (const float*)d_in[30];
  const float* fuse_b   = (const float*)d_in[31];
  const int*   lengths  = (const int*)d_in[32];
  float* out = (float*)d_out;

  float* ws       = (float*)d_ws;
  float* x_comp   = ws;                                   // B*T*V
  float* stats    = x_comp + (size_t)NB*NT*NV;            // B*97
  float* ctx      = stats + NB*97;                        // B*64
  float* h0       = ctx + NB*64;                          // B*128
  float* c0      = h0 + NB*128;                           // B*128
  float* cgF      = c0 + NB*128;                          // B*256
  float* cgB      = cgF + NB*256;                         // B*256
  float* hidden   = cgB + NB*256;                         // B*T*128
  float* feat_imp = hidden + (size_t)NB*NT*128;           // B*T*V
  // total ~25.4M floats ~= 102 MB

  k_stats<<<NB, 256, 0, stream>>>(values, masks, lengths, x_comp, stats);
  k_feat<<<256, 512, 76032, stream>>>(x_comp, feat_W, feat_b, nl1_W, nl1_b, nl2_W, nl2_b, feat_imp);
  k_cmlp<<<NB, 64, 0, stream>>>(stats, cmlp_W1, cmlp_b1, cmlp_W2, cmlp_b2, ctx);
  k_gru<<<NB, 512, 0, stream>>>(x_comp, rain_f, rain_b, lengths, gru_Wih, gru_Whh, gru_bih, gru_bhh, ctx);
  k_init<<<NB, 256, 0, stream>>>(ctx, init_W, init_b,
                                 lstmf_Wih, lstmf_bih, lstmf_bhh,
                                 lstmb_Wih, lstmb_bih, lstmb_bhh,
                                 h0, c0, cgF, cgB, hidden);
  dim3 lgrid(64, 2);
  k_lstm<<<lgrid, 512, 75264, stream>>>(x_comp, masks,
                                        lstmf_Wih, lstmf_Whh, lstmb_Wih, lstmb_Whh,
                                        cgF, cgB, h0, c0, lengths, hidden);
  k_final<<<2048, 512, 0, stream>>>(values, masks, feat_imp, hidden,
                                    rimp_W, rimp_b, fuse_W, fuse_b, lengths, out);
}